// Round 1
// baseline (432.890 us; speedup 1.0000x reference)
//
#include <hip/hip_runtime.h>
#include <cstdint>

#define N_NODES 20000
#define N_EDGES 320000
#define ET (N_EDGES + N_NODES)   // edges + self loops
#define IN_DIM 128
#define HID 64
#define HEADS 8
#define F1 (HEADS * HID)         // 512
#define OUT_DIM 64
#define NEG_SLOPE 0.2f

// ---------------- CSR build (dst-sorted) ----------------
__global__ void hist_kernel(const int* __restrict__ ei, int* __restrict__ deg) {
  int e = blockIdx.x * 256 + threadIdx.x;
  if (e >= ET) return;
  int dst = (e < N_EDGES) ? ei[N_EDGES + e] : (e - N_EDGES);
  atomicAdd(&deg[dst], 1);
}

__global__ void scan_kernel(const int* __restrict__ deg, int* __restrict__ off,
                            int* __restrict__ pos) {
  __shared__ int buf[1024];
  __shared__ int carry_s;
  if (threadIdx.x == 0) carry_s = 0;
  __syncthreads();
  for (int base = 0; base < N_NODES; base += 1024) {
    int i = base + threadIdx.x;
    int v = (i < N_NODES) ? deg[i] : 0;
    buf[threadIdx.x] = v;
    __syncthreads();
    for (int s = 1; s < 1024; s <<= 1) {
      int tv = (threadIdx.x >= s) ? buf[threadIdx.x - s] : 0;
      __syncthreads();
      buf[threadIdx.x] += tv;
      __syncthreads();
    }
    int incl = buf[threadIdx.x];
    int carry = carry_s;
    if (i < N_NODES) { int ex = carry + incl - v; off[i] = ex; pos[i] = ex; }
    __syncthreads();
    if (threadIdx.x == 1023) carry_s = carry + incl;
    __syncthreads();
  }
  if (threadIdx.x == 0) off[N_NODES] = carry_s;
}

__global__ void scatter_kernel(const int* __restrict__ ei, int* __restrict__ pos,
                               int* __restrict__ csr_src) {
  int e = blockIdx.x * 256 + threadIdx.x;
  if (e >= ET) return;
  int src, dst;
  if (e < N_EDGES) { src = ei[e]; dst = ei[N_EDGES + e]; }
  else             { src = e - N_EDGES; dst = src; }
  int slot = atomicAdd(&pos[dst], 1);
  csr_src[slot] = src;
}

// ---------------- fp32 tiled GEMM: C[M,NC] = A[M,K] @ B[K,NC] ----------------
__device__ __forceinline__ int bswz(int col, int k4) {
  return col * 16 + ((k4 ^ ((col >> 2) & 3)) << 2);
}

template <int TM, int TN>
__global__ __launch_bounds__(256) void gemm_kernel(
    const float* __restrict__ A, const float* __restrict__ B,
    float* __restrict__ C, int M, int K, int NC) {
  constexpr int BM = 16 * TM;
  constexpr int BN = 16 * TN;
  __shared__ float As[BM * 20];   // [row][k] stride 20 (bank spread)
  __shared__ float Bs[BN * 16];   // [col][k] xor-swizzled
  const int t = threadIdx.x;
  const int tx = t & 15, ty = t >> 4;
  const int m0 = blockIdx.y * BM, n0 = blockIdx.x * BN;
  float acc[TM][TN] = {};
  for (int k0 = 0; k0 < K; k0 += 16) {
    // stage A tile BMx16
#pragma unroll
    for (int q = 0; q < BM / 64; ++q) {
      int f = t + 256 * q;
      int row = f >> 2, kc = (f & 3) << 2;
      int gr = m0 + row;
      if (gr > M - 1) gr = M - 1;
      float4 v = *reinterpret_cast<const float4*>(&A[(size_t)gr * K + k0 + kc]);
      *reinterpret_cast<float4*>(&As[row * 20 + kc]) = v;
    }
    // stage B tile 16xBN, transposed + swizzled
    {
      constexpr int GPC = 256 / BN;
      int col = t & (BN - 1);
      int kb = t / BN;
#pragma unroll
      for (int q = 0; q < BN / 64; ++q) {
        int k4 = kb + GPC * q;
        const float* bp = &B[(size_t)(k0 + k4 * 4) * NC + n0 + col];
        float4 v;
        v.x = bp[0 * NC]; v.y = bp[(size_t)1 * NC];
        v.z = bp[(size_t)2 * NC]; v.w = bp[(size_t)3 * NC];
        *reinterpret_cast<float4*>(&Bs[bswz(col, k4)]) = v;
      }
    }
    __syncthreads();
#pragma unroll
    for (int k4 = 0; k4 < 4; ++k4) {
      float4 a[TM], b[TN];
#pragma unroll
      for (int i = 0; i < TM; ++i)
        a[i] = *reinterpret_cast<const float4*>(&As[(ty + 16 * i) * 20 + k4 * 4]);
#pragma unroll
      for (int j = 0; j < TN; ++j)
        b[j] = *reinterpret_cast<const float4*>(&Bs[bswz(tx + 16 * j, k4)]);
#pragma unroll
      for (int i = 0; i < TM; ++i)
#pragma unroll
        for (int j = 0; j < TN; ++j)
          acc[i][j] += a[i].x * b[j].x + a[i].y * b[j].y +
                       a[i].z * b[j].z + a[i].w * b[j].w;
    }
    __syncthreads();
  }
#pragma unroll
  for (int i = 0; i < TM; ++i) {
    int r = m0 + ty + 16 * i;
    if (r < M) {
#pragma unroll
      for (int j = 0; j < TN; ++j)
        C[(size_t)r * NC + n0 + tx + 16 * j] = acc[i][j];
    }
  }
}

// ---------------- per-node attention scalars a_s, a_d ----------------
template <int H, int C>
__global__ void asd_kernel(const float* __restrict__ Hf, const float* __restrict__ atts,
                           const float* __restrict__ attd, float* __restrict__ asd) {
  int n = blockIdx.x * blockDim.x + threadIdx.x;
  if (n >= N_NODES) return;
  float s[H] = {}, d[H] = {};
  const float4* hp = reinterpret_cast<const float4*>(Hf + (size_t)n * H * C);
  const float4* ap = reinterpret_cast<const float4*>(atts);
  const float4* dp = reinterpret_cast<const float4*>(attd);
#pragma unroll
  for (int j = 0; j < H * C / 4; ++j) {
    int h = j / (C / 4);
    float4 hv = hp[j], av = ap[j], dv = dp[j];
    s[h] += hv.x * av.x + hv.y * av.y + hv.z * av.z + hv.w * av.w;
    d[h] += hv.x * dv.x + hv.y * dv.y + hv.z * dv.z + hv.w * dv.w;
  }
#pragma unroll
  for (int h = 0; h < H; ++h) {
    asd[(size_t)n * 2 * H + h] = s[h];
    asd[(size_t)n * 2 * H + H + h] = d[h];
  }
}

// ---------------- edge softmax -> alpha (one wave per dst node) ----------------
template <int H>
__global__ void alpha_kernel(const int* __restrict__ off, const int* __restrict__ csrs,
                             const float* __restrict__ asd, float* __restrict__ alpha) {
  int node = blockIdx.x * 4 + (threadIdx.x >> 6);
  if (node >= N_NODES) return;
  int lane = threadIdx.x & 63;
  int h = lane % H;
  int j = lane / H;
  constexpr int STEP = 64 / H;
  int s0 = off[node], s1 = off[node + 1];
  float adst = asd[(size_t)node * 2 * H + H + h];
  float mx = -1e30f;
  for (int i = s0 + j; i < s1; i += STEP) {
    float xv = asd[(size_t)csrs[i] * 2 * H + h] + adst;
    xv = xv > 0.f ? xv : NEG_SLOPE * xv;
    mx = fmaxf(mx, xv);
  }
#pragma unroll
  for (int s = H; s < 64; s <<= 1) mx = fmaxf(mx, __shfl_xor(mx, s));
  float sum = 0.f;
  for (int i = s0 + j; i < s1; i += STEP) {
    float xv = asd[(size_t)csrs[i] * 2 * H + h] + adst;
    xv = xv > 0.f ? xv : NEG_SLOPE * xv;
    sum += __expf(xv - mx);
  }
#pragma unroll
  for (int s = H; s < 64; s <<= 1) sum += __shfl_xor(sum, s);
  float inv = 1.f / sum;
  for (int i = s0 + j; i < s1; i += STEP) {
    float xv = asd[(size_t)csrs[i] * 2 * H + h] + adst;
    xv = xv > 0.f ? xv : NEG_SLOPE * xv;
    alpha[(size_t)i * H + h] = __expf(xv - mx) * inv;
  }
}

// ---------------- aggregation: out[dst] = sum alpha * H[src] ----------------
__global__ __launch_bounds__(512) void agg1_kernel(
    const int* __restrict__ off, const int* __restrict__ csrs,
    const float* __restrict__ alpha, const float* __restrict__ H1f,
    const float* __restrict__ b1, float* __restrict__ X2) {
  int node = blockIdx.x;
  int t = threadIdx.x;          // feature index 0..511, h = t>>6
  int h = t >> 6;
  int s0 = off[node], s1 = off[node + 1];
  float acc = 0.f;
  for (int i = s0; i < s1; ++i) {
    int src = csrs[i];
    float a = alpha[(size_t)i * 8 + h];
    acc += a * H1f[(size_t)src * F1 + t];
  }
  float v = acc + b1[t];
  X2[(size_t)node * F1 + t] = v > 0.f ? v : 0.f;   // fused ReLU
}

__global__ __launch_bounds__(64) void agg2_kernel(
    const int* __restrict__ off, const int* __restrict__ csrs,
    const float* __restrict__ alpha, const float* __restrict__ H2f,
    const float* __restrict__ b2, float* __restrict__ out) {
  int node = blockIdx.x;
  int c = threadIdx.x;
  int s0 = off[node], s1 = off[node + 1];
  float acc = 0.f;
  for (int i = s0; i < s1; ++i)
    acc += alpha[i] * H2f[(size_t)csrs[i] * OUT_DIM + c];
  out[(size_t)node * OUT_DIM + c] = acc + b2[c];
}

// ---------------- launch ----------------
extern "C" void kernel_launch(void* const* d_in, const int* in_sizes, int n_in,
                              void* d_out, int out_size, void* d_ws, size_t ws_size,
                              hipStream_t stream) {
  const float* x        = (const float*)d_in[0];
  const int*   ei       = (const int*)  d_in[1];
  const float* W1       = (const float*)d_in[2];
  const float* att_src1 = (const float*)d_in[3];
  const float* att_dst1 = (const float*)d_in[4];
  const float* b1       = (const float*)d_in[5];
  const float* W2       = (const float*)d_in[6];
  const float* att_src2 = (const float*)d_in[7];
  const float* att_dst2 = (const float*)d_in[8];
  const float* b2       = (const float*)d_in[9];
  float* out = (float*)d_out;

  char* w = (char*)d_ws;
  auto alloc = [&](size_t bytes) {
    char* p = w;
    w += (bytes + 255) & ~(size_t)255;
    return p;
  };
  float* H1     = (float*)alloc((size_t)N_NODES * F1 * 4);
  float* X2     = (float*)alloc((size_t)N_NODES * F1 * 4);
  float* H2     = (float*)alloc((size_t)N_NODES * OUT_DIM * 4);
  float* asd1   = (float*)alloc((size_t)N_NODES * 16 * 4);
  float* asd2   = (float*)alloc((size_t)N_NODES * 2 * 4);
  float* alpha1 = (float*)alloc((size_t)ET * 8 * 4);
  float* alpha2 = (float*)alloc((size_t)ET * 4);
  int* deg      = (int*)alloc((size_t)N_NODES * 4);
  int* off      = (int*)alloc((size_t)(N_NODES + 1) * 4);
  int* pos      = (int*)alloc((size_t)N_NODES * 4);
  int* csrsrc   = (int*)alloc((size_t)ET * 4);

  // CSR build
  hipMemsetAsync(deg, 0, (size_t)N_NODES * 4, stream);
  hist_kernel<<<(ET + 255) / 256, 256, 0, stream>>>(ei, deg);
  scan_kernel<<<1, 1024, 0, stream>>>(deg, off, pos);
  scatter_kernel<<<(ET + 255) / 256, 256, 0, stream>>>(ei, pos, csrsrc);

  // ---- Layer 1 ----
  gemm_kernel<8, 8><<<dim3(F1 / 128, (N_NODES + 127) / 128), 256, 0, stream>>>(
      x, W1, H1, N_NODES, IN_DIM, F1);
  asd_kernel<8, 64><<<(N_NODES + 255) / 256, 256, 0, stream>>>(H1, att_src1, att_dst1, asd1);
  alpha_kernel<8><<<(N_NODES + 3) / 4, 256, 0, stream>>>(off, csrsrc, asd1, alpha1);
  agg1_kernel<<<N_NODES, 512, 0, stream>>>(off, csrsrc, alpha1, H1, b1, X2);

  // ---- Layer 2 ----
  gemm_kernel<8, 4><<<dim3(1, (N_NODES + 127) / 128), 256, 0, stream>>>(
      X2, W2, H2, N_NODES, F1, OUT_DIM);
  asd_kernel<1, 64><<<(N_NODES + 255) / 256, 256, 0, stream>>>(H2, att_src2, att_dst2, asd2);
  alpha_kernel<1><<<(N_NODES + 3) / 4, 256, 0, stream>>>(off, csrsrc, asd2, alpha2);
  agg2_kernel<<<N_NODES, 64, 0, stream>>>(off, csrsrc, alpha2, H2, b2, out);
}

// Round 2
// 213.949 us; speedup vs baseline: 2.0233x; 2.0233x over previous
//
#include <hip/hip_runtime.h>
#include <cstdint>

#define N_NODES 20000
#define N_EDGES 320000
#define ET (N_EDGES + N_NODES)   // edges + self loops
#define IN_DIM 128
#define HID 64
#define HEADS 8
#define F1 (HEADS * HID)         // 512
#define OUT_DIM 64
#define NEG_SLOPE 0.2f

typedef __attribute__((ext_vector_type(8))) short bf16x8;
typedef __attribute__((ext_vector_type(4))) float f32x4;

__device__ __forceinline__ ushort f2bf(float f) {
  uint32_t u = __float_as_uint(f);
  uint32_t r = (u + 0x7fffu + ((u >> 16) & 1u)) >> 16;
  return (ushort)r;
}
__device__ __forceinline__ float bfu_lo(uint32_t p) { return __uint_as_float(p << 16); }
__device__ __forceinline__ float bfu_hi(uint32_t p) { return __uint_as_float(p & 0xffff0000u); }

// ---------------- casts ----------------
__global__ void cast_kernel(const float* __restrict__ in, ushort* __restrict__ out, int n4) {
  int i = blockIdx.x * 256 + threadIdx.x;
  if (i >= n4) return;
  float4 v = reinterpret_cast<const float4*>(in)[i];
  ushort4 o;
  o.x = f2bf(v.x); o.y = f2bf(v.y); o.z = f2bf(v.z); o.w = f2bf(v.w);
  reinterpret_cast<ushort4*>(out)[i] = o;
}

__global__ void castT_kernel(const float* __restrict__ in, ushort* __restrict__ out,
                             int R, int C) {   // out[c][r] = bf16(in[r][c])
  int idx = blockIdx.x * 256 + threadIdx.x;
  if (idx >= R * C) return;
  int r = idx / C, c = idx - r * C;
  out[(size_t)c * R + r] = f2bf(in[idx]);
}

// ---------------- CSR build (dst-sorted) ----------------
__global__ void hist_kernel(const int* __restrict__ ei, int* __restrict__ deg) {
  int e = blockIdx.x * 256 + threadIdx.x;
  if (e >= ET) return;
  int dst = (e < N_EDGES) ? ei[N_EDGES + e] : (e - N_EDGES);
  atomicAdd(&deg[dst], 1);
}

__global__ void scan_kernel(const int* __restrict__ deg, int* __restrict__ off,
                            int* __restrict__ pos) {
  __shared__ int wsum[16];
  __shared__ int carry_s;
  int lane = threadIdx.x & 63, wid = threadIdx.x >> 6;
  if (threadIdx.x == 0) carry_s = 0;
  __syncthreads();
  for (int base = 0; base < N_NODES; base += 1024) {
    int i = base + threadIdx.x;
    int v = (i < N_NODES) ? deg[i] : 0;
    int s = v;
#pragma unroll
    for (int d = 1; d < 64; d <<= 1) {
      int u = __shfl_up(s, d);
      if (lane >= d) s += u;
    }
    if (lane == 63) wsum[wid] = s;
    __syncthreads();
    if (wid == 0) {
      int ws = (lane < 16) ? wsum[lane] : 0;
#pragma unroll
      for (int d = 1; d < 16; d <<= 1) {
        int u = __shfl_up(ws, d);
        if (lane >= d) ws += u;
      }
      if (lane < 16) wsum[lane] = ws;
    }
    __syncthreads();
    int wbase = (wid > 0) ? wsum[wid - 1] : 0;
    int carry = carry_s;
    int incl = carry + wbase + s;
    if (i < N_NODES) { off[i] = incl - v; pos[i] = incl - v; }
    __syncthreads();
    if (threadIdx.x == 1023) carry_s = incl;
    __syncthreads();
  }
  if (threadIdx.x == 0) off[N_NODES] = carry_s;
}

__global__ void scatter_kernel(const int* __restrict__ ei, int* __restrict__ pos,
                               int* __restrict__ csr_src) {
  int e = blockIdx.x * 256 + threadIdx.x;
  if (e >= ET) return;
  int src, dst;
  if (e < N_EDGES) { src = ei[e]; dst = ei[N_EDGES + e]; }
  else             { src = e - N_EDGES; dst = src; }
  int slot = atomicAdd(&pos[dst], 1);
  csr_src[slot] = src;
}

// ---------------- bf16 MFMA GEMM: C[M,NC] = A[M,K] @ BT[NC,K]^T ----------------
// BM=128, BK=32, 4 waves in 2x2 grid, wave tile 64 x (TN*16).
__device__ __forceinline__ int swz(int r, int kg) { return kg ^ ((r >> 1) & 3); }

template <int TN>
__global__ __launch_bounds__(256) void mfma_gemm_kernel(
    const ushort* __restrict__ A, const ushort* __restrict__ BT,
    ushort* __restrict__ Cb, int M, int K, int NC) {
  constexpr int BM = 128;
  constexpr int BN = 2 * TN * 16;
  __shared__ ushort As[BM * 32];
  __shared__ ushort Bs[BN * 32];
  const int t = threadIdx.x;
  const int lane = t & 63, wid = t >> 6;
  const int wr = wid >> 1, wc = wid & 1;
  const int m0 = blockIdx.y * BM, n0 = blockIdx.x * BN;
  f32x4 acc[4][TN] = {};
  const int srow = t >> 2, kg = t & 3;

  for (int k0 = 0; k0 < K; k0 += 32) {
#pragma unroll
    for (int q = 0; q < 2; ++q) {            // A tile: 128 rows
      int r = srow + 64 * q;
      int gr = m0 + r; if (gr >= M) gr = M - 1;
      bf16x8 v = *reinterpret_cast<const bf16x8*>(&A[(size_t)gr * K + k0 + kg * 8]);
      *reinterpret_cast<bf16x8*>(&As[r * 32 + swz(r, kg) * 8]) = v;
    }
#pragma unroll
    for (int q = 0; q < BN / 64; ++q) {      // B tile: BN rows of BT
      int r = srow + 64 * q;
      int gn = n0 + r;
      bf16x8 v = *reinterpret_cast<const bf16x8*>(&BT[(size_t)gn * K + k0 + kg * 8]);
      *reinterpret_cast<bf16x8*>(&Bs[r * 32 + swz(r, kg) * 8]) = v;
    }
    __syncthreads();
    int kq = lane >> 4;
    int rr = lane & 15;
    bf16x8 af[4], bfv[TN];
#pragma unroll
    for (int i = 0; i < 4; ++i) {
      int r = wr * 64 + i * 16 + rr;
      af[i] = *reinterpret_cast<const bf16x8*>(&As[r * 32 + swz(r, kq) * 8]);
    }
#pragma unroll
    for (int j = 0; j < TN; ++j) {
      int r = wc * (TN * 16) + j * 16 + rr;
      bfv[j] = *reinterpret_cast<const bf16x8*>(&Bs[r * 32 + swz(r, kq) * 8]);
    }
#pragma unroll
    for (int i = 0; i < 4; ++i)
#pragma unroll
      for (int j = 0; j < TN; ++j)
        acc[i][j] = __builtin_amdgcn_mfma_f32_16x16x32_bf16(af[i], bfv[j], acc[i][j], 0, 0, 0);
    __syncthreads();
  }
  int cr0 = (lane >> 4) * 4;
  int cc = lane & 15;
#pragma unroll
  for (int i = 0; i < 4; ++i)
#pragma unroll
    for (int j = 0; j < TN; ++j)
#pragma unroll
      for (int r = 0; r < 4; ++r) {
        int gm = m0 + wr * 64 + i * 16 + cr0 + r;
        int gn = n0 + wc * TN * 16 + j * 16 + cc;
        if (gm < M) Cb[(size_t)gm * NC + gn] = f2bf(acc[i][j][r]);
      }
}

// ---------------- per-node attention scalars (bf16 input) ----------------
template <int H, int C>
__global__ void asd_kernel(const ushort* __restrict__ Hb, const float* __restrict__ atts,
                           const float* __restrict__ attd, float* __restrict__ asd) {
  int n = blockIdx.x * blockDim.x + threadIdx.x;
  if (n >= N_NODES) return;
  float s[H] = {}, d[H] = {};
  const uint4* hp = reinterpret_cast<const uint4*>(Hb + (size_t)n * H * C);
  const float4* ap = reinterpret_cast<const float4*>(atts);
  const float4* dp = reinterpret_cast<const float4*>(attd);
#pragma unroll
  for (int j = 0; j < H * C / 8; ++j) {
    int h = j / (C / 8);
    uint4 pv = hp[j];
    float4 a0 = ap[2 * j], a1 = ap[2 * j + 1];
    float4 d0 = dp[2 * j], d1 = dp[2 * j + 1];
    float e0 = bfu_lo(pv.x), e1 = bfu_hi(pv.x), e2 = bfu_lo(pv.y), e3 = bfu_hi(pv.y);
    float e4 = bfu_lo(pv.z), e5 = bfu_hi(pv.z), e6 = bfu_lo(pv.w), e7 = bfu_hi(pv.w);
    s[h] += e0*a0.x + e1*a0.y + e2*a0.z + e3*a0.w + e4*a1.x + e5*a1.y + e6*a1.z + e7*a1.w;
    d[h] += e0*d0.x + e1*d0.y + e2*d0.z + e3*d0.w + e4*d1.x + e5*d1.y + e6*d1.z + e7*d1.w;
  }
#pragma unroll
  for (int h = 0; h < H; ++h) {
    asd[(size_t)n * 2 * H + h] = s[h];
    asd[(size_t)n * 2 * H + H + h] = d[h];
  }
}

// ---------------- edge softmax -> alpha (one wave per dst node) ----------------
template <int H>
__global__ void alpha_kernel(const int* __restrict__ off, const int* __restrict__ csrs,
                             const float* __restrict__ asd, float* __restrict__ alpha) {
  int node = blockIdx.x * 4 + (threadIdx.x >> 6);
  if (node >= N_NODES) return;
  int lane = threadIdx.x & 63;
  int h = lane % H;
  int j = lane / H;
  constexpr int STEP = 64 / H;
  int s0 = off[node], s1 = off[node + 1];
  float adst = asd[(size_t)node * 2 * H + H + h];
  float mx = -1e30f;
  for (int i = s0 + j; i < s1; i += STEP) {
    float xv = asd[(size_t)csrs[i] * 2 * H + h] + adst;
    xv = xv > 0.f ? xv : NEG_SLOPE * xv;
    mx = fmaxf(mx, xv);
  }
#pragma unroll
  for (int s = H; s < 64; s <<= 1) mx = fmaxf(mx, __shfl_xor(mx, s));
  float sum = 0.f;
  for (int i = s0 + j; i < s1; i += STEP) {
    float xv = asd[(size_t)csrs[i] * 2 * H + h] + adst;
    xv = xv > 0.f ? xv : NEG_SLOPE * xv;
    sum += __expf(xv - mx);
  }
#pragma unroll
  for (int s = H; s < 64; s <<= 1) sum += __shfl_xor(sum, s);
  float inv = 1.f / sum;
  for (int i = s0 + j; i < s1; i += STEP) {
    float xv = asd[(size_t)csrs[i] * 2 * H + h] + adst;
    xv = xv > 0.f ? xv : NEG_SLOPE * xv;
    alpha[(size_t)i * H + h] = __expf(xv - mx) * inv;
  }
}

// ---------------- aggregation L1 (bf16 gather, fused bias+ReLU, bf16 out) ----------------
__global__ __launch_bounds__(256) void agg1_kernel(
    const int* __restrict__ off, const int* __restrict__ csrs,
    const float* __restrict__ alpha, const ushort* __restrict__ H1b,
    const float* __restrict__ b1, ushort* __restrict__ X2b) {
  int node = blockIdx.x;
  int t = threadIdx.x;                 // features 2t, 2t+1; head = t>>5
  int h = t >> 5;
  int s0 = off[node], s1 = off[node + 1];
  const uint32_t* Hp = reinterpret_cast<const uint32_t*>(H1b);
  float a0 = 0.f, a1 = 0.f;
  int i = s0;
  for (; i + 1 < s1; i += 2) {
    int src0 = csrs[i], src1 = csrs[i + 1];
    float al0 = alpha[(size_t)i * 8 + h], al1 = alpha[(size_t)(i + 1) * 8 + h];
    uint32_t p0 = Hp[(size_t)src0 * 256 + t];
    uint32_t p1 = Hp[(size_t)src1 * 256 + t];
    a0 += al0 * bfu_lo(p0) + al1 * bfu_lo(p1);
    a1 += al0 * bfu_hi(p0) + al1 * bfu_hi(p1);
  }
  if (i < s1) {
    float al = alpha[(size_t)i * 8 + h];
    uint32_t p = Hp[(size_t)csrs[i] * 256 + t];
    a0 += al * bfu_lo(p);
    a1 += al * bfu_hi(p);
  }
  float v0 = fmaxf(a0 + b1[2 * t], 0.f);
  float v1 = fmaxf(a1 + b1[2 * t + 1], 0.f);
  reinterpret_cast<uint32_t*>(X2b)[(size_t)node * 256 + t] =
      (uint32_t)f2bf(v0) | ((uint32_t)f2bf(v1) << 16);
}

// ---------------- aggregation L2 (bf16 gather, fp32 out) ----------------
__global__ __launch_bounds__(256) void agg2_kernel(
    const int* __restrict__ off, const int* __restrict__ csrs,
    const float* __restrict__ alpha, const ushort* __restrict__ H2b,
    const float* __restrict__ b2, float* __restrict__ out) {
  int node = blockIdx.x * 4 + (threadIdx.x >> 6);
  if (node >= N_NODES) return;
  int lane = threadIdx.x & 63;
  int s0 = off[node], s1 = off[node + 1];
  float acc = 0.f;
  int i = s0;
  for (; i + 1 < s1; i += 2) {
    int sa = csrs[i], sb = csrs[i + 1];
    float ala = alpha[i], alb = alpha[i + 1];
    float va = __uint_as_float((uint32_t)H2b[(size_t)sa * 64 + lane] << 16);
    float vb = __uint_as_float((uint32_t)H2b[(size_t)sb * 64 + lane] << 16);
    acc += ala * va + alb * vb;
  }
  if (i < s1)
    acc += alpha[i] * __uint_as_float((uint32_t)H2b[(size_t)csrs[i] * 64 + lane] << 16);
  out[(size_t)node * 64 + lane] = acc + b2[lane];
}

// ---------------- launch ----------------
extern "C" void kernel_launch(void* const* d_in, const int* in_sizes, int n_in,
                              void* d_out, int out_size, void* d_ws, size_t ws_size,
                              hipStream_t stream) {
  const float* x        = (const float*)d_in[0];
  const int*   ei       = (const int*)  d_in[1];
  const float* W1       = (const float*)d_in[2];
  const float* att_src1 = (const float*)d_in[3];
  const float* att_dst1 = (const float*)d_in[4];
  const float* b1       = (const float*)d_in[5];
  const float* W2       = (const float*)d_in[6];
  const float* att_src2 = (const float*)d_in[7];
  const float* att_dst2 = (const float*)d_in[8];
  const float* b2       = (const float*)d_in[9];
  float* out = (float*)d_out;

  char* w = (char*)d_ws;
  auto alloc = [&](size_t bytes) {
    char* p = w;
    w += (bytes + 255) & ~(size_t)255;
    return p;
  };
  ushort* xb     = (ushort*)alloc((size_t)N_NODES * IN_DIM * 2);
  ushort* W1T    = (ushort*)alloc((size_t)F1 * IN_DIM * 2);
  ushort* W2T    = (ushort*)alloc((size_t)OUT_DIM * F1 * 2);
  ushort* H1b    = (ushort*)alloc((size_t)N_NODES * F1 * 2);
  ushort* X2b    = (ushort*)alloc((size_t)N_NODES * F1 * 2);
  ushort* H2b    = (ushort*)alloc((size_t)N_NODES * OUT_DIM * 2);
  float* asd1    = (float*)alloc((size_t)N_NODES * 16 * 4);
  float* asd2    = (float*)alloc((size_t)N_NODES * 2 * 4);
  float* alpha1  = (float*)alloc((size_t)ET * 8 * 4);
  float* alpha2  = (float*)alloc((size_t)ET * 4);
  int* deg       = (int*)alloc((size_t)N_NODES * 4);
  int* off       = (int*)alloc((size_t)(N_NODES + 1) * 4);
  int* pos       = (int*)alloc((size_t)N_NODES * 4);
  int* csrsrc    = (int*)alloc((size_t)ET * 4);

  // CSR build
  hipMemsetAsync(deg, 0, (size_t)N_NODES * 4, stream);
  hist_kernel<<<(ET + 255) / 256, 256, 0, stream>>>(ei, deg);
  scan_kernel<<<1, 1024, 0, stream>>>(deg, off, pos);
  scatter_kernel<<<(ET + 255) / 256, 256, 0, stream>>>(ei, pos, csrsrc);

  // casts
  cast_kernel<<<(N_NODES * IN_DIM / 4 + 255) / 256, 256, 0, stream>>>(x, xb, N_NODES * IN_DIM / 4);
  castT_kernel<<<(IN_DIM * F1 + 255) / 256, 256, 0, stream>>>(W1, W1T, IN_DIM, F1);
  castT_kernel<<<(F1 * OUT_DIM + 255) / 256, 256, 0, stream>>>(W2, W2T, F1, OUT_DIM);

  // ---- Layer 1 ----
  mfma_gemm_kernel<4><<<dim3(F1 / 128, (N_NODES + 127) / 128), 256, 0, stream>>>(
      xb, W1T, H1b, N_NODES, IN_DIM, F1);
  asd_kernel<8, 64><<<(N_NODES + 255) / 256, 256, 0, stream>>>(H1b, att_src1, att_dst1, asd1);
  alpha_kernel<8><<<(N_NODES + 3) / 4, 256, 0, stream>>>(off, csrsrc, asd1, alpha1);
  agg1_kernel<<<N_NODES, 256, 0, stream>>>(off, csrsrc, alpha1, H1b, b1, X2b);

  // ---- Layer 2 ----
  mfma_gemm_kernel<2><<<dim3(1, (N_NODES + 127) / 128), 256, 0, stream>>>(
      X2b, W2T, H2b, N_NODES, F1, OUT_DIM);
  asd_kernel<1, 64><<<(N_NODES + 255) / 256, 256, 0, stream>>>(H2b, att_src2, att_dst2, asd2);
  alpha_kernel<1><<<(N_NODES + 3) / 4, 256, 0, stream>>>(off, csrsrc, asd2, alpha2);
  agg2_kernel<<<(N_NODES + 3) / 4, 256, 0, stream>>>(off, csrsrc, alpha2, H2b, b2, out);
}

// Round 3
// 173.461 us; speedup vs baseline: 2.4956x; 1.2334x over previous
//
#include <hip/hip_runtime.h>
#include <cstdint>

#define N_NODES 20000
#define N_EDGES 320000
#define ET (N_EDGES + N_NODES)   // edges + self loops
#define IN_DIM 128
#define HID 64
#define HEADS 8
#define F1 (HEADS * HID)         // 512
#define OUT_DIM 64
#define NEG_SLOPE 0.2f
#define NB_SCAN 20               // ceil(20000/1024)

typedef __attribute__((ext_vector_type(8))) short bf16x8;
typedef __attribute__((ext_vector_type(4))) float f32x4;

__device__ __forceinline__ ushort f2bf(float f) {
  uint32_t u = __float_as_uint(f);
  uint32_t r = (u + 0x7fffu + ((u >> 16) & 1u)) >> 16;
  return (ushort)r;
}
__device__ __forceinline__ float bfu_lo(uint32_t p) { return __uint_as_float(p << 16); }
__device__ __forceinline__ float bfu_hi(uint32_t p) { return __uint_as_float(p & 0xffff0000u); }

// ---------------- casts ----------------
__global__ void cast_kernel(const float* __restrict__ in, ushort* __restrict__ out, int n4) {
  int i = blockIdx.x * 256 + threadIdx.x;
  if (i >= n4) return;
  float4 v = reinterpret_cast<const float4*>(in)[i];
  ushort4 o;
  o.x = f2bf(v.x); o.y = f2bf(v.y); o.z = f2bf(v.z); o.w = f2bf(v.w);
  reinterpret_cast<ushort4*>(out)[i] = o;
}

__global__ void castT_kernel(const float* __restrict__ in, ushort* __restrict__ out,
                             int R, int C) {   // out[c][r] = bf16(in[r][c])
  int idx = blockIdx.x * 256 + threadIdx.x;
  if (idx >= R * C) return;
  int r = idx / C, c = idx - r * C;
  out[(size_t)c * R + r] = f2bf(in[idx]);
}

// ---------------- CSR build (dst-sorted) ----------------
__global__ void hist_kernel(const int* __restrict__ ei, int* __restrict__ deg) {
  int e = blockIdx.x * 256 + threadIdx.x;
  if (e >= ET) return;
  int dst = (e < N_EDGES) ? ei[N_EDGES + e] : (e - N_EDGES);
  atomicAdd(&deg[dst], 1);
}

// phase A: per-block exclusive scan + block sums
__global__ __launch_bounds__(1024) void scan_a(const int* __restrict__ deg,
                                               int* __restrict__ off,
                                               int* __restrict__ bsum) {
  __shared__ int wsum[16];
  int i = blockIdx.x * 1024 + threadIdx.x;
  int lane = threadIdx.x & 63, wid = threadIdx.x >> 6;
  int v = (i < N_NODES) ? deg[i] : 0;
  int s = v;
#pragma unroll
  for (int d = 1; d < 64; d <<= 1) {
    int u = __shfl_up(s, d);
    if (lane >= d) s += u;
  }
  if (lane == 63) wsum[wid] = s;
  __syncthreads();
  if (wid == 0) {
    int ws = (lane < 16) ? wsum[lane] : 0;
#pragma unroll
    for (int d = 1; d < 16; d <<= 1) {
      int u = __shfl_up(ws, d);
      if (lane >= d) ws += u;
    }
    if (lane < 16) wsum[lane] = ws;
  }
  __syncthreads();
  int wbase = (wid > 0) ? wsum[wid - 1] : 0;
  int incl = wbase + s;
  if (i < N_NODES) off[i] = incl - v;
  if (threadIdx.x == 1023) bsum[blockIdx.x] = incl;
}

// phase B: scan the block sums (single wave)
__global__ void scan_b(const int* __restrict__ bsum, int* __restrict__ boff,
                       int* __restrict__ off) {
  int lane = threadIdx.x;
  int orig = (lane < NB_SCAN) ? bsum[lane] : 0;
  int v = orig;
#pragma unroll
  for (int d = 1; d < 64; d <<= 1) {
    int u = __shfl_up(v, d);
    if (lane >= d) v += u;
  }
  if (lane < NB_SCAN) boff[lane] = v - orig;
  if (lane == NB_SCAN - 1) off[N_NODES] = v;
}

// phase C: add block offsets
__global__ __launch_bounds__(1024) void scan_c(const int* __restrict__ boff,
                                               int* __restrict__ off,
                                               int* __restrict__ pos) {
  int i = blockIdx.x * 1024 + threadIdx.x;
  if (i >= N_NODES) return;
  int o = off[i] + boff[blockIdx.x];
  off[i] = o;
  pos[i] = o;
}

__global__ void scatter_kernel(const int* __restrict__ ei, int* __restrict__ pos,
                               int* __restrict__ csr_src) {
  int e = blockIdx.x * 256 + threadIdx.x;
  if (e >= ET) return;
  int src, dst;
  if (e < N_EDGES) { src = ei[e]; dst = ei[N_EDGES + e]; }
  else             { src = e - N_EDGES; dst = src; }
  int slot = atomicAdd(&pos[dst], 1);
  csr_src[slot] = src;
}

// ---------------- bf16 MFMA GEMM: C[M,NC] = A[M,K] @ BT[NC,K]^T ----------------
// BM=128, BK=32, 4 waves in 2x2 grid, wave tile 64 x (TN*16).
// FUSE_ASD: each wave's TN*16=64 cols are exactly one head -> fused a_s/a_d.
__device__ __forceinline__ int swz(int r, int kg) { return kg ^ ((r >> 1) & 3); }

template <int TN, bool FUSE_ASD>
__global__ __launch_bounds__(256) void mfma_gemm_kernel(
    const ushort* __restrict__ A, const ushort* __restrict__ BT,
    ushort* __restrict__ Cb, int M, int K, int NC,
    const float* __restrict__ atts, const float* __restrict__ attd,
    float* __restrict__ asd) {
  constexpr int BM = 128;
  constexpr int BN = 2 * TN * 16;
  __shared__ ushort As[BM * 32];
  __shared__ ushort Bs[BN * 32];
  const int t = threadIdx.x;
  const int lane = t & 63, wid = t >> 6;
  const int wr = wid >> 1, wc = wid & 1;
  const int m0 = blockIdx.y * BM, n0 = blockIdx.x * BN;
  f32x4 acc[4][TN] = {};
  const int srow = t >> 2, kg = t & 3;

  for (int k0 = 0; k0 < K; k0 += 32) {
#pragma unroll
    for (int q = 0; q < 2; ++q) {            // A tile: 128 rows
      int r = srow + 64 * q;
      int gr = m0 + r; if (gr >= M) gr = M - 1;
      bf16x8 v = *reinterpret_cast<const bf16x8*>(&A[(size_t)gr * K + k0 + kg * 8]);
      *reinterpret_cast<bf16x8*>(&As[r * 32 + swz(r, kg) * 8]) = v;
    }
#pragma unroll
    for (int q = 0; q < BN / 64; ++q) {      // B tile: BN rows of BT
      int r = srow + 64 * q;
      int gn = n0 + r;
      bf16x8 v = *reinterpret_cast<const bf16x8*>(&BT[(size_t)gn * K + k0 + kg * 8]);
      *reinterpret_cast<bf16x8*>(&Bs[r * 32 + swz(r, kg) * 8]) = v;
    }
    __syncthreads();
    int kq = lane >> 4;
    int rr = lane & 15;
    bf16x8 af[4], bfv[TN];
#pragma unroll
    for (int i = 0; i < 4; ++i) {
      int r = wr * 64 + i * 16 + rr;
      af[i] = *reinterpret_cast<const bf16x8*>(&As[r * 32 + swz(r, kq) * 8]);
    }
#pragma unroll
    for (int j = 0; j < TN; ++j) {
      int r = wc * (TN * 16) + j * 16 + rr;
      bfv[j] = *reinterpret_cast<const bf16x8*>(&Bs[r * 32 + swz(r, kq) * 8]);
    }
#pragma unroll
    for (int i = 0; i < 4; ++i)
#pragma unroll
      for (int j = 0; j < TN; ++j)
        acc[i][j] = __builtin_amdgcn_mfma_f32_16x16x32_bf16(af[i], bfv[j], acc[i][j], 0, 0, 0);
    __syncthreads();
  }
  const int cr0 = (lane >> 4) * 4;
  const int cc = lane & 15;
#pragma unroll
  for (int i = 0; i < 4; ++i)
#pragma unroll
    for (int j = 0; j < TN; ++j)
#pragma unroll
      for (int r = 0; r < 4; ++r) {
        int gm = m0 + wr * 64 + i * 16 + cr0 + r;
        int gn = n0 + wc * TN * 16 + j * 16 + cc;
        if (gm < M) Cb[(size_t)gm * NC + gn] = f2bf(acc[i][j][r]);
      }
  if constexpr (FUSE_ASD) {
    // wave (wr,wc) owns rows m0+wr*64..+63, head hh over its 64 cols
    int hh = (n0 >> 6) + wc;
    float as_v[TN], ad_v[TN];
#pragma unroll
    for (int j = 0; j < TN; ++j) {
      as_v[j] = atts[hh * 64 + j * 16 + cc];
      ad_v[j] = attd[hh * 64 + j * 16 + cc];
    }
#pragma unroll
    for (int i = 0; i < 4; ++i)
#pragma unroll
      for (int r = 0; r < 4; ++r) {
        float ps = 0.f, pd = 0.f;
#pragma unroll
        for (int j = 0; j < TN; ++j) {
          ps += acc[i][j][r] * as_v[j];
          pd += acc[i][j][r] * ad_v[j];
        }
#pragma unroll
        for (int s = 1; s < 16; s <<= 1) {
          ps += __shfl_xor(ps, s);
          pd += __shfl_xor(pd, s);
        }
        int row = m0 + wr * 64 + i * 16 + cr0 + r;
        if (cc == 0 && row < M) {
          asd[(size_t)row * 16 + hh] = ps;
          asd[(size_t)row * 16 + 8 + hh] = pd;
        }
      }
  }
}

// ---------------- per-node attention scalars (layer 2, H=1) ----------------
template <int H, int C>
__global__ void asd_kernel(const ushort* __restrict__ Hb, const float* __restrict__ atts,
                           const float* __restrict__ attd, float* __restrict__ asd) {
  int n = blockIdx.x * blockDim.x + threadIdx.x;
  if (n >= N_NODES) return;
  float s[H] = {}, d[H] = {};
  const uint4* hp = reinterpret_cast<const uint4*>(Hb + (size_t)n * H * C);
  const float4* ap = reinterpret_cast<const float4*>(atts);
  const float4* dp = reinterpret_cast<const float4*>(attd);
#pragma unroll
  for (int j = 0; j < H * C / 8; ++j) {
    int h = j / (C / 8);
    uint4 pv = hp[j];
    float4 a0 = ap[2 * j], a1 = ap[2 * j + 1];
    float4 d0 = dp[2 * j], d1 = dp[2 * j + 1];
    float e0 = bfu_lo(pv.x), e1 = bfu_hi(pv.x), e2 = bfu_lo(pv.y), e3 = bfu_hi(pv.y);
    float e4 = bfu_lo(pv.z), e5 = bfu_hi(pv.z), e6 = bfu_lo(pv.w), e7 = bfu_hi(pv.w);
    s[h] += e0*a0.x + e1*a0.y + e2*a0.z + e3*a0.w + e4*a1.x + e5*a1.y + e6*a1.z + e7*a1.w;
    d[h] += e0*d0.x + e1*d0.y + e2*d0.z + e3*d0.w + e4*d1.x + e5*d1.y + e6*d1.z + e7*d1.w;
  }
#pragma unroll
  for (int h = 0; h < H; ++h) {
    asd[(size_t)n * 2 * H + h] = s[h];
    asd[(size_t)n * 2 * H + H + h] = d[h];
  }
}

// ---------------- edge softmax -> alpha (one wave per dst node) ----------------
template <int H>
__global__ void alpha_kernel(const int* __restrict__ off, const int* __restrict__ csrs,
                             const float* __restrict__ asd, float* __restrict__ alpha) {
  int node = blockIdx.x * 4 + (threadIdx.x >> 6);
  if (node >= N_NODES) return;
  int lane = threadIdx.x & 63;
  int h = lane % H;
  int j = lane / H;
  constexpr int STEP = 64 / H;
  int s0 = off[node], s1 = off[node + 1];
  float adst = asd[(size_t)node * 2 * H + H + h];
  float mx = -1e30f;
  for (int i = s0 + j; i < s1; i += STEP) {
    float xv = asd[(size_t)csrs[i] * 2 * H + h] + adst;
    xv = xv > 0.f ? xv : NEG_SLOPE * xv;
    mx = fmaxf(mx, xv);
  }
#pragma unroll
  for (int s = H; s < 64; s <<= 1) mx = fmaxf(mx, __shfl_xor(mx, s));
  float sum = 0.f;
  for (int i = s0 + j; i < s1; i += STEP) {
    float xv = asd[(size_t)csrs[i] * 2 * H + h] + adst;
    xv = xv > 0.f ? xv : NEG_SLOPE * xv;
    sum += __expf(xv - mx);
  }
#pragma unroll
  for (int s = H; s < 64; s <<= 1) sum += __shfl_xor(sum, s);
  float inv = 1.f / sum;
  for (int i = s0 + j; i < s1; i += STEP) {
    float xv = asd[(size_t)csrs[i] * 2 * H + h] + adst;
    xv = xv > 0.f ? xv : NEG_SLOPE * xv;
    alpha[(size_t)i * H + h] = __expf(xv - mx) * inv;
  }
}

// ---------------- aggregation L1: 128 thr/node, uint2 gather, unroll 4 ----------------
__global__ __launch_bounds__(128) void agg1_kernel(
    const int* __restrict__ off, const int* __restrict__ csrs,
    const float* __restrict__ alpha, const ushort* __restrict__ H1b,
    const float* __restrict__ b1, ushort* __restrict__ X2b) {
  int node = blockIdx.x;
  int t = threadIdx.x;                 // features 4t..4t+3, head = t>>4
  int h = t >> 4;
  int s0 = off[node], s1 = off[node + 1];
  const uint2* Hp = reinterpret_cast<const uint2*>(H1b);   // row stride 128
  float a0 = 0.f, a1 = 0.f, a2 = 0.f, a3 = 0.f;
  int i = s0;
  for (; i + 4 <= s1; i += 4) {
    int sA = csrs[i], sB = csrs[i + 1], sC = csrs[i + 2], sD = csrs[i + 3];
    float lA = alpha[(size_t)i * 8 + h];
    float lB = alpha[(size_t)(i + 1) * 8 + h];
    float lC = alpha[(size_t)(i + 2) * 8 + h];
    float lD = alpha[(size_t)(i + 3) * 8 + h];
    uint2 pA = Hp[(size_t)sA * 128 + t];
    uint2 pB = Hp[(size_t)sB * 128 + t];
    uint2 pC = Hp[(size_t)sC * 128 + t];
    uint2 pD = Hp[(size_t)sD * 128 + t];
    a0 += lA * bfu_lo(pA.x) + lB * bfu_lo(pB.x) + lC * bfu_lo(pC.x) + lD * bfu_lo(pD.x);
    a1 += lA * bfu_hi(pA.x) + lB * bfu_hi(pB.x) + lC * bfu_hi(pC.x) + lD * bfu_hi(pD.x);
    a2 += lA * bfu_lo(pA.y) + lB * bfu_lo(pB.y) + lC * bfu_lo(pC.y) + lD * bfu_lo(pD.y);
    a3 += lA * bfu_hi(pA.y) + lB * bfu_hi(pB.y) + lC * bfu_hi(pC.y) + lD * bfu_hi(pD.y);
  }
  for (; i < s1; ++i) {
    float l = alpha[(size_t)i * 8 + h];
    uint2 p = Hp[(size_t)csrs[i] * 128 + t];
    a0 += l * bfu_lo(p.x); a1 += l * bfu_hi(p.x);
    a2 += l * bfu_lo(p.y); a3 += l * bfu_hi(p.y);
  }
  float v0 = fmaxf(a0 + b1[4 * t], 0.f);
  float v1 = fmaxf(a1 + b1[4 * t + 1], 0.f);
  float v2 = fmaxf(a2 + b1[4 * t + 2], 0.f);
  float v3 = fmaxf(a3 + b1[4 * t + 3], 0.f);
  uint2 o;
  o.x = (uint32_t)f2bf(v0) | ((uint32_t)f2bf(v1) << 16);
  o.y = (uint32_t)f2bf(v2) | ((uint32_t)f2bf(v3) << 16);
  reinterpret_cast<uint2*>(X2b)[(size_t)node * 128 + t] = o;
}

// ---------------- aggregation L2 (bf16 gather, unroll 4, fp32 out) ----------------
__global__ __launch_bounds__(256) void agg2_kernel(
    const int* __restrict__ off, const int* __restrict__ csrs,
    const float* __restrict__ alpha, const ushort* __restrict__ H2b,
    const float* __restrict__ b2, float* __restrict__ out) {
  int node = blockIdx.x * 4 + (threadIdx.x >> 6);
  if (node >= N_NODES) return;
  int lane = threadIdx.x & 63;
  int s0 = off[node], s1 = off[node + 1];
  float acc = 0.f;
  int i = s0;
  for (; i + 4 <= s1; i += 4) {
    int sA = csrs[i], sB = csrs[i + 1], sC = csrs[i + 2], sD = csrs[i + 3];
    float lA = alpha[i], lB = alpha[i + 1], lC = alpha[i + 2], lD = alpha[i + 3];
    float vA = __uint_as_float((uint32_t)H2b[(size_t)sA * 64 + lane] << 16);
    float vB = __uint_as_float((uint32_t)H2b[(size_t)sB * 64 + lane] << 16);
    float vC = __uint_as_float((uint32_t)H2b[(size_t)sC * 64 + lane] << 16);
    float vD = __uint_as_float((uint32_t)H2b[(size_t)sD * 64 + lane] << 16);
    acc += lA * vA + lB * vB + lC * vC + lD * vD;
  }
  for (; i < s1; ++i)
    acc += alpha[i] * __uint_as_float((uint32_t)H2b[(size_t)csrs[i] * 64 + lane] << 16);
  out[(size_t)node * 64 + lane] = acc + b2[lane];
}

// ---------------- launch ----------------
extern "C" void kernel_launch(void* const* d_in, const int* in_sizes, int n_in,
                              void* d_out, int out_size, void* d_ws, size_t ws_size,
                              hipStream_t stream) {
  const float* x        = (const float*)d_in[0];
  const int*   ei       = (const int*)  d_in[1];
  const float* W1       = (const float*)d_in[2];
  const float* att_src1 = (const float*)d_in[3];
  const float* att_dst1 = (const float*)d_in[4];
  const float* b1       = (const float*)d_in[5];
  const float* W2       = (const float*)d_in[6];
  const float* att_src2 = (const float*)d_in[7];
  const float* att_dst2 = (const float*)d_in[8];
  const float* b2       = (const float*)d_in[9];
  float* out = (float*)d_out;

  char* w = (char*)d_ws;
  auto alloc = [&](size_t bytes) {
    char* p = w;
    w += (bytes + 255) & ~(size_t)255;
    return p;
  };
  ushort* xb     = (ushort*)alloc((size_t)N_NODES * IN_DIM * 2);
  ushort* W1T    = (ushort*)alloc((size_t)F1 * IN_DIM * 2);
  ushort* W2T    = (ushort*)alloc((size_t)OUT_DIM * F1 * 2);
  ushort* H1b    = (ushort*)alloc((size_t)N_NODES * F1 * 2);
  ushort* X2b    = (ushort*)alloc((size_t)N_NODES * F1 * 2);
  ushort* H2b    = (ushort*)alloc((size_t)N_NODES * OUT_DIM * 2);
  float* asd1    = (float*)alloc((size_t)N_NODES * 16 * 4);
  float* asd2    = (float*)alloc((size_t)N_NODES * 2 * 4);
  float* alpha1  = (float*)alloc((size_t)ET * 8 * 4);
  float* alpha2  = (float*)alloc((size_t)ET * 4);
  int* deg       = (int*)alloc((size_t)N_NODES * 4);
  int* off       = (int*)alloc((size_t)(N_NODES + 1) * 4);
  int* pos       = (int*)alloc((size_t)N_NODES * 4);
  int* csrsrc    = (int*)alloc((size_t)ET * 4);
  int* bsum      = (int*)alloc((size_t)NB_SCAN * 4);
  int* boff      = (int*)alloc((size_t)NB_SCAN * 4);

  // CSR build
  hipMemsetAsync(deg, 0, (size_t)N_NODES * 4, stream);
  hist_kernel<<<(ET + 255) / 256, 256, 0, stream>>>(ei, deg);
  scan_a<<<NB_SCAN, 1024, 0, stream>>>(deg, off, bsum);
  scan_b<<<1, 64, 0, stream>>>(bsum, boff, off);
  scan_c<<<NB_SCAN, 1024, 0, stream>>>(boff, off, pos);
  scatter_kernel<<<(ET + 255) / 256, 256, 0, stream>>>(ei, pos, csrsrc);

  // casts
  cast_kernel<<<(N_NODES * IN_DIM / 4 + 255) / 256, 256, 0, stream>>>(x, xb, N_NODES * IN_DIM / 4);
  castT_kernel<<<(IN_DIM * F1 + 255) / 256, 256, 0, stream>>>(W1, W1T, IN_DIM, F1);
  castT_kernel<<<(F1 * OUT_DIM + 255) / 256, 256, 0, stream>>>(W2, W2T, F1, OUT_DIM);

  // ---- Layer 1 (asd fused into GEMM epilogue) ----
  mfma_gemm_kernel<4, true><<<dim3(F1 / 128, (N_NODES + 127) / 128), 256, 0, stream>>>(
      xb, W1T, H1b, N_NODES, IN_DIM, F1, att_src1, att_dst1, asd1);
  alpha_kernel<8><<<(N_NODES + 3) / 4, 256, 0, stream>>>(off, csrsrc, asd1, alpha1);
  agg1_kernel<<<N_NODES, 128, 0, stream>>>(off, csrsrc, alpha1, H1b, b1, X2b);

  // ---- Layer 2 ----
  mfma_gemm_kernel<2, false><<<dim3(1, (N_NODES + 127) / 128), 256, 0, stream>>>(
      X2b, W2T, H2b, N_NODES, F1, OUT_DIM, nullptr, nullptr, nullptr);
  asd_kernel<1, 64><<<(N_NODES + 255) / 256, 256, 0, stream>>>(H2b, att_src2, att_dst2, asd2);
  alpha_kernel<1><<<(N_NODES + 3) / 4, 256, 0, stream>>>(off, csrsrc, asd2, alpha2);
  agg2_kernel<<<(N_NODES + 3) / 4, 256, 0, stream>>>(off, csrsrc, alpha2, H2b, b2, out);
}